// Round 4
// baseline (423.432 us; speedup 1.0000x reference)
//
#include <hip/hip_runtime.h>
#include <hip/hip_bf16.h>

// out[b,t,n,f] = in[b,t,n,f] * 1.1 if n < set_size[b,t] else 0
// B=32, T=64, N=128, F=256, fp32. Pure streaming, zero reuse.
//
// R2 change (still under test - R3 bench timed out): flat grid-stride
// decomposition for CU load balance. Previous version: 1 block per (b,t),
// grid = 2048 = exactly the co-residency limit (256 CU x 8 blocks) -> no
// dispatcher slack, and per-block work varies 2:1 with set. Tail CUs ran
// ~15% long; kernel ended on the slowest CU (~80us vs 63us floor).
// Grid-stride spreads rows uniformly: every CU averages thousands of
// row-samples -> near-perfect balance.
//
// Coalescing/uniformity preserved: a wave's 64 lanes cover one aligned
// 64-vfloat4 (1 KiB) row, so bt, n, and the mask test are wave-uniform.
// sizes[bt] is readfirstlane-hoisted -> scalar (s_load) path, keeping the
// vector-memory pipe purely for the streaming traffic.

typedef float vfloat4 __attribute__((ext_vector_type(4)));

#define N_DIM 128
#define F_DIM 256
#define ROW_F4 (F_DIM / 4)              // 64 vfloat4 per row
#define BT_F4 (N_DIM * ROW_F4)          // 8192 vfloat4 per (b,t)
#define BLOCK 256
#define GRID 2048                       // 256 CU x 8 blocks co-resident
#define SCALE 1.1f                      // ALPHA + BETA

__global__ __launch_bounds__(BLOCK) void mask_scale_kernel(
    const vfloat4* __restrict__ in,
    const int* __restrict__ sizes,
    vfloat4* __restrict__ out,
    const int total_f4) {
    const int stride = GRID * BLOCK;
    const vfloat4 z = (vfloat4)(0.f);

#pragma unroll 4
    for (int j = blockIdx.x * BLOCK + threadIdx.x; j < total_f4; j += stride) {
        const int bt = __builtin_amdgcn_readfirstlane(j >> 13);  // j / BT_F4, wave-uniform
        const int n  = (j >> 6) & (N_DIM - 1);
        const int set = sizes[bt];            // scalar load, L2-resident 8KB table
        vfloat4 v = z;
        if (n < set) {                        // wave-uniform branch
            v = in[j];
            v *= SCALE;
        }
        out[j] = v;
    }
}

extern "C" void kernel_launch(void* const* d_in, const int* in_sizes, int n_in,
                              void* d_out, int out_size, void* d_ws, size_t ws_size,
                              hipStream_t stream) {
    const vfloat4* in = (const vfloat4*)d_in[0];
    const int* sizes = (const int*)d_in[1];
    vfloat4* out = (vfloat4*)d_out;

    const int bt_count = in_sizes[1];          // B*T = 2048
    const int total_f4 = bt_count * BT_F4;     // 16.78M vfloat4
    mask_scale_kernel<<<GRID, BLOCK, 0, stream>>>(in, sizes, out, total_f4);
}

// Round 6
// 411.505 us; speedup vs baseline: 1.0290x; 1.0290x over previous
//
#include <hip/hip_runtime.h>
#include <hip/hip_bf16.h>

// out[b,t,n,f] = in[b,t,n,f] * 1.1 if n < set_size[b,t] else 0
// B=32, T=64, N=128, F=256, fp32. Pure streaming, zero reuse -> nontemporal
// loads/stores. One block per (b,t). Two branch-free loops: scaled rows then
// zero rows. split = set*64 is 64-aligned so loop bounds are wave-uniform.
//
// R4/R5: REVERT to the best harness-verified configuration (409.4 us).
// Session A/B record (dur_us, 2 poison fills ~330us are fixed harness cost):
//   nt + unroll4 (this)  : 409.4   <- best
//   nt + unroll8         : 412.3
//   plain cached         : 417.9   (nt-removal theory: refuted)
//   flat grid-stride     : 423.4   (CU-imbalance theory: refuted)
// Kernel-dispatch estimate ~80us vs 63us traffic floor (402 MB @ 6.3 TB/s
// mixed-stream ceiling); residual ~= run-to-run fill noise.

typedef float vfloat4 __attribute__((ext_vector_type(4)));

#define N_DIM 128
#define F_DIM 256
#define ROW_F4 (F_DIM / 4)              // 64 vfloat4 per row
#define BT_F4 (N_DIM * ROW_F4)          // 8192 vfloat4 per (b,t)
#define BLOCK 256
#define SCALE 1.1f                      // ALPHA + BETA

__global__ __launch_bounds__(BLOCK) void mask_scale_kernel(
    const vfloat4* __restrict__ in,
    const int* __restrict__ sizes,
    vfloat4* __restrict__ out) {
    const int bt = blockIdx.x;                 // 0 .. B*T-1
    const int set = sizes[bt];                 // wave-uniform
    const long long base = (long long)bt * BT_F4;
    const int split = set * ROW_F4;            // first vfloat4 of the zero region

    const vfloat4* in_b = in + base;
    vfloat4* out_b = out + base;

    // Region 1: rows [0, set) — read, scale, store. Streaming, nontemporal.
#pragma unroll 4
    for (int j = threadIdx.x; j < split; j += BLOCK) {
        vfloat4 v = __builtin_nontemporal_load(&in_b[j]);
        v *= SCALE;
        __builtin_nontemporal_store(v, &out_b[j]);
    }

    // Region 2: rows [set, 128) — zero-fill only, no input read.
    const vfloat4 z = (vfloat4)(0.f);
#pragma unroll 4
    for (int j = split + (int)threadIdx.x; j < BT_F4; j += BLOCK) {
        __builtin_nontemporal_store(z, &out_b[j]);
    }
}

extern "C" void kernel_launch(void* const* d_in, const int* in_sizes, int n_in,
                              void* d_out, int out_size, void* d_ws, size_t ws_size,
                              hipStream_t stream) {
    const vfloat4* in = (const vfloat4*)d_in[0];
    const int* sizes = (const int*)d_in[1];
    vfloat4* out = (vfloat4*)d_out;

    const int bt_count = in_sizes[1];          // B*T = 2048
    mask_scale_kernel<<<bt_count, BLOCK, 0, stream>>>(in, sizes, out);
}